// Round 3
// baseline (736.652 us; speedup 1.0000x reference)
//
#include <hip/hip_runtime.h>
#include <hip/hip_bf16.h>
#include <cstddef>

#define H_   22
#define T_   1000
#define B_   64
#define NSEQ (B_ * H_)      // 1408 sequences (B*C, C==22)
#define KP   22             // conv out channels
#define TP   10             // pooled time positions
#define POOL 100
#define CSTR 488            // padded dot length (484 -> 488, 61 x uint4 of bf16)

__device__ __forceinline__ float sigm(float x) {
    return __fdividef(1.f, 1.f + __expf(-x));     // saturates correctly
}
__device__ __forceinline__ float tanhfast(float x) {
    return 1.f - __fdividef(2.f, __expf(2.f * x) + 1.f);
}
__device__ __forceinline__ void unpk8(const uint4 v, float* f) {
    f[0] = __uint_as_float(v.x << 16);
    f[1] = __uint_as_float(v.x & 0xffff0000u);
    f[2] = __uint_as_float(v.y << 16);
    f[3] = __uint_as_float(v.y & 0xffff0000u);
    f[4] = __uint_as_float(v.z << 16);
    f[5] = __uint_as_float(v.z & 0xffff0000u);
    f[6] = __uint_as_float(v.w << 16);
    f[7] = __uint_as_float(v.w & 0xffff0000u);
}

// ---------------------------------------------------------------------------
// Kernel 1: batched independent LSTMs (fp32 in, bf16 hs out).
// 1 wave / block, 2 sequences / wave: lane = (half = lane>>5, hh = lane&31),
// lanes with hh>=22 idle. Each lane holds the 4 gate rows of W_hh in regs
// and its own h-unit value (hmine) in a register. The h-vector broadcast is
// done with ds_bpermute (per-half pull from lanes half*32+j) — pure register
// dataflow between steps: no LDS buffer, no barrier, no lgkmcnt(0) drain.
// Gate dot chains split 2x11 to halve dependent-FMA latency.
// hs layout: [b][t][c][h] (contiguous 484-elem dot vector per (b,t)).
// ---------------------------------------------------------------------------
__global__ __launch_bounds__(64) void lstm_k(
    const float* __restrict__ xin,   // [NSEQ][T_]
    const float* __restrict__ W_ih,  // [88]
    const float* __restrict__ W_hh,  // [88][22]
    const float* __restrict__ b_ih,  // [88]
    const float* __restrict__ b_hh,  // [88]
    __hip_bfloat16* __restrict__ hsw)// [B_][T_][22][22]
{
    const int lane = threadIdx.x;
    const int half = lane >> 5;
    const int hh   = lane & 31;
    if (hh >= H_) return;
    const int seq = blockIdx.x * 2 + half;
    const int b   = seq / H_;
    const int c   = seq - b * H_;

    float Wg_[4][H_];
    float wih[4], bias[4];
    #pragma unroll
    for (int g = 0; g < 4; ++g) {
        const int row = g * H_ + hh;
        wih[g]  = W_ih[row];
        bias[g] = b_ih[row] + b_hh[row];
        #pragma unroll
        for (int j = 0; j < H_; ++j)
            Wg_[g][j] = W_hh[row * H_ + j];
    }

    float creg  = 0.f;
    float hmine = 0.f;                       // this lane's h-unit
    const int bidx = (lane & 32) << 2;       // half*128: byte index of lane half*32
    const float* xp = xin + (size_t)seq * T_;
    float xc = xp[0];
    __hip_bfloat16* hout = hsw + ((size_t)b * T_ * (H_ * H_)) + c * H_ + hh;

    for (int t = 0; t < T_; ++t) {
        const float xn = (t + 1 < T_) ? xp[t + 1] : 0.f;

        float a0 = fmaf(xc, wih[0], bias[0]);
        float a1 = fmaf(xc, wih[1], bias[1]);
        float a2 = fmaf(xc, wih[2], bias[2]);
        float a3 = fmaf(xc, wih[3], bias[3]);
        float b0 = 0.f, b1 = 0.f, b2 = 0.f, b3 = 0.f;
        const int hbits = __float_as_int(hmine);
        #pragma unroll
        for (int j = 0; j < 11; ++j) {
            const float hb = __int_as_float(
                __builtin_amdgcn_ds_bpermute(bidx + 4 * j, hbits));
            a0 = fmaf(Wg_[0][j], hb, a0);
            a1 = fmaf(Wg_[1][j], hb, a1);
            a2 = fmaf(Wg_[2][j], hb, a2);
            a3 = fmaf(Wg_[3][j], hb, a3);
        }
        #pragma unroll
        for (int j = 11; j < 22; ++j) {
            const float hb = __int_as_float(
                __builtin_amdgcn_ds_bpermute(bidx + 4 * j, hbits));
            b0 = fmaf(Wg_[0][j], hb, b0);
            b1 = fmaf(Wg_[1][j], hb, b1);
            b2 = fmaf(Wg_[2][j], hb, b2);
            b3 = fmaf(Wg_[3][j], hb, b3);
        }
        a0 += b0; a1 += b1; a2 += b2; a3 += b3;

        const float ig = sigm(a0);
        const float fg = sigm(a1);
        const float gg = tanhfast(a2);
        const float og = sigm(a3);
        creg = fmaf(fg, creg, ig * gg);
        const float hnew = og * tanhfast(creg);
        hmine = hnew;
        hout[0] = __float2bfloat16(hnew);
        hout += H_ * H_;
        xc = xn;
    }
}

// ---------------------------------------------------------------------------
// Kernel 2: conv(22ch, kh=22) + bias + ELU + BN(eval) + AvgPool(100).
// One block per (b, pool window p). hs tile (phased: 40/40/20 t) in LDS
// (bf16, padded stride 488 = 61 uint4/row); conv_w staged with coalesced
// linear global reads, scattered (transposed) into LDS as bf16.
// Register tile: 4 t x 2 k per thread (110/128 active).
// ---------------------------------------------------------------------------
__global__ __launch_bounds__(128) void conv_k(
    const __hip_bfloat16* __restrict__ hsw,  // [B_][T_][22][22]
    const float* __restrict__ conv_w,        // [22][22][22]
    const float* __restrict__ conv_b,        // [22]
    const float* __restrict__ bn_g,
    const float* __restrict__ bn_b,
    const float* __restrict__ bn_m,
    const float* __restrict__ bn_v,
    float* __restrict__ pooled)              // [B_][22][10]
{
    __shared__ __align__(16) __hip_bfloat16 wl[22 * CSTR];
    __shared__ __align__(16) __hip_bfloat16 hl[40 * CSTR];
    __shared__ float pp[22 * TP];

    const int tid = threadIdx.x;
    const int b = blockIdx.x / TP;
    const int p = blockIdx.x - b * TP;

    // stage conv_w: coalesced linear read, transposed scatter to LDS:
    // conv_w[k][i][r] -> wl[k][r*22 + i]
    for (int d = tid; d < 22 * 484; d += 128) {
        const float w = conv_w[d];
        const int k = d / 484, rem = d - k * 484;
        const int i2 = rem / 22, r = rem - i2 * 22;
        wl[k * CSTR + r * 22 + i2] = __float2bfloat16(w);
    }
    for (int d = tid; d < 22; d += 128)
        *reinterpret_cast<uint2*>(&wl[d * CSTR + 484]) = make_uint2(0u, 0u);

    const int k2 = tid % 11;          // k pair index
    const int t4 = tid / 11;          // 4-row tile index (0..9 valid)
    const bool act = (tid < 110);
    const int k0 = 2 * k2, k1 = 2 * k2 + 1;

    float cb[2], mn[2], bt[2], inv[2];
    #pragma unroll
    for (int j = 0; j < 2; ++j) {
        const int k = k0 + j;
        cb[j] = conv_b[k];
        mn[j] = bn_m[k];
        bt[j] = bn_b[k];
        inv[j] = bn_g[k] * __frsqrt_rn(bn_v[k] + 1e-5f);
    }

    float poolsum[2] = {0.f, 0.f};
    const __hip_bfloat16* src = hsw + ((size_t)b * T_ + (size_t)p * POOL) * 484;
    const uint4* wl4 = reinterpret_cast<const uint4*>(wl);

    for (int ph = 0; ph < 3; ++ph) {
        const int rows = (ph == 2) ? 20 : 40;
        const uint2* gsrc = reinterpret_cast<const uint2*>(src + (size_t)(ph * 40) * 484);
        const int n2 = rows * 121;
        for (int idx = tid; idx < n2; idx += 128) {
            const int tr = idx / 121, col = idx - tr * 121;
            reinterpret_cast<uint2*>(&hl[tr * CSTR])[col] = gsrc[idx];
        }
        for (int idx = tid; idx < rows; idx += 128)
            *reinterpret_cast<uint2*>(&hl[idx * CSTR + 484]) = make_uint2(0u, 0u);
        __syncthreads();

        if (act && t4 < ((ph == 2) ? 5 : 10)) {
            float acc[4][2];
            #pragma unroll
            for (int i = 0; i < 4; ++i) { acc[i][0] = 0.f; acc[i][1] = 0.f; }
            const uint4* hl4 = reinterpret_cast<const uint4*>(hl);
            const int r0 = t4 * 4;
            const int w0 = k0 * 61, w1 = k1 * 61;
            for (int cch = 0; cch < 61; ++cch) {
                float wf[8], wg[8];
                unpk8(wl4[w0 + cch], wf);
                unpk8(wl4[w1 + cch], wg);
                #pragma unroll
                for (int i = 0; i < 4; ++i) {
                    float hf[8];
                    unpk8(hl4[(r0 + i) * 61 + cch], hf);
                    #pragma unroll
                    for (int e = 0; e < 8; ++e) {
                        acc[i][0] = fmaf(hf[e], wf[e], acc[i][0]);
                        acc[i][1] = fmaf(hf[e], wg[e], acc[i][1]);
                    }
                }
            }
            #pragma unroll
            for (int i = 0; i < 4; ++i) {
                #pragma unroll
                for (int j = 0; j < 2; ++j) {
                    const float s = acc[i][j] + cb[j];
                    const float e = (s > 0.f) ? s : (__expf(s) - 1.f);
                    poolsum[j] += fmaf(e - mn[j], inv[j], bt[j]);
                }
            }
        }
        __syncthreads();
    }

    if (act) {
        pp[k0 * TP + t4] = poolsum[0];
        pp[k1 * TP + t4] = poolsum[1];
    }
    __syncthreads();
    if (tid < 22) {
        float s = 0.f;
        #pragma unroll
        for (int q = 0; q < TP; ++q) s += pp[tid * TP + q];
        pooled[((size_t)b * 22 + tid) * TP + p] = s * 0.01f;
    }
}

// ---------------------------------------------------------------------------
// Kernel 3: FC [64,220] x [220,4]^T + bias -> fp32 out. One thread per output.
// ---------------------------------------------------------------------------
__global__ __launch_bounds__(256) void fc_k(
    const float* __restrict__ pooled,  // [64][220] (idx = k*10+p)
    const float* __restrict__ fc_w,    // [4][220]
    const float* __restrict__ fc_b,    // [4]
    float* __restrict__ out)           // [64][4]
{
    const int tid = threadIdx.x;
    const int b = tid >> 2, n = tid & 3;
    const float* pv = pooled + b * 220;
    const float* wv = fc_w + n * 220;
    float s = fc_b[n];
    #pragma unroll 4
    for (int j = 0; j < 220; ++j)
        s = fmaf(pv[j], wv[j], s);
    out[tid] = s;
}

extern "C" void kernel_launch(void* const* d_in, const int* in_sizes, int n_in,
                              void* d_out, int out_size, void* d_ws, size_t ws_size,
                              hipStream_t stream) {
    const float* xin    = (const float*)d_in[0];
    const float* W_ih   = (const float*)d_in[1];
    const float* W_hh   = (const float*)d_in[2];
    const float* b_ih   = (const float*)d_in[3];
    const float* b_hh   = (const float*)d_in[4];
    const float* conv_w = (const float*)d_in[5];
    const float* conv_b = (const float*)d_in[6];
    const float* bn_g   = (const float*)d_in[7];
    const float* bn_b   = (const float*)d_in[8];
    const float* bn_m   = (const float*)d_in[9];
    const float* bn_v   = (const float*)d_in[10];
    const float* fc_w   = (const float*)d_in[11];
    const float* fc_b   = (const float*)d_in[12];

    __hip_bfloat16* hsw = (__hip_bfloat16*)d_ws;                        // 61,952,000 B
    float* pooled = (float*)((char*)d_ws + (size_t)B_ * T_ * 484 * 2);  // 56,320 B

    lstm_k<<<NSEQ / 2, 64, 0, stream>>>(xin, W_ih, W_hh, b_ih, b_hh, hsw);
    conv_k<<<B_ * TP, 128, 0, stream>>>(hsw, conv_w, conv_b, bn_g, bn_b, bn_m, bn_v, pooled);
    fc_k<<<1, 256, 0, stream>>>(pooled, fc_w, fc_b, (float*)d_out);
}

// Round 4
// 712.823 us; speedup vs baseline: 1.0334x; 1.0334x over previous
//
#include <hip/hip_runtime.h>
#include <hip/hip_bf16.h>
#include <cstddef>

#define H_   22
#define T_   1000
#define B_   64
#define NSEQ (B_ * H_)      // 1408 sequences (B*C, C==22)
#define KP   22             // conv out channels
#define TP   10             // pooled time positions
#define POOL 100
#define CSTR 488            // hl row stride in bf16 (484 pad-> 488 = 61 uint4)

__device__ __forceinline__ float sigm(float x) {
    return __fdividef(1.f, 1.f + __expf(-x));     // saturates correctly
}
__device__ __forceinline__ float tanhfast(float x) {
    return 1.f - __fdividef(2.f, __expf(2.f * x) + 1.f);
}
__device__ __forceinline__ void unpk8(const uint4 v, float* f) {
    f[0] = __uint_as_float(v.x << 16);
    f[1] = __uint_as_float(v.x & 0xffff0000u);
    f[2] = __uint_as_float(v.y << 16);
    f[3] = __uint_as_float(v.y & 0xffff0000u);
    f[4] = __uint_as_float(v.z << 16);
    f[5] = __uint_as_float(v.z & 0xffff0000u);
    f[6] = __uint_as_float(v.w << 16);
    f[7] = __uint_as_float(v.w & 0xffff0000u);
}

// ---------------------------------------------------------------------------
// Kernel 1: batched independent LSTMs (fp32 in, bf16 hs out).
// 1 wave / block, 2 sequences / wave: lane = (half = lane>>5, hh = lane&31),
// lanes hh>=22 idle. Each lane holds its 4 gate rows of W_hh in VGPRs.
// __launch_bounds__(64, 1): min-waves/EU=1 -> max VGPR budget. Round-3
// profiling showed VGPR_Count=80 (< the 96 needed) + FETCH_SIZE=2.88 GB:
// the compiler was re-fetching ~half of W_hh from memory EVERY timestep,
// putting global-load latency on the serial critical path. This is the fix.
// h-exchange via LDS (write b32, read back 6x ds_read_b128); single-wave
// block => DS pipe in-order per wave; wave_barrier() pins compiler order.
// hs layout: [b][t][c][h] (contiguous 484-elem dot vector per (b,t)).
// ---------------------------------------------------------------------------
__global__ __launch_bounds__(64, 1) void lstm_k(
    const float* __restrict__ xin,   // [NSEQ][T_]
    const float* __restrict__ W_ih,  // [88]
    const float* __restrict__ W_hh,  // [88][22]
    const float* __restrict__ b_ih,  // [88]
    const float* __restrict__ b_hh,  // [88]
    __hip_bfloat16* __restrict__ hsw)// [B_][T_][22][22]
{
    __shared__ __align__(16) float hl[2][24];
    const int lane = threadIdx.x;
    const int half = lane >> 5;
    const int hh   = lane & 31;
    if (hh >= H_) return;
    const int seq = blockIdx.x * 2 + half;
    const int b   = seq / H_;
    const int c   = seq - b * H_;

    float Wg_[4][H_];
    float wih[4], bias[4];
    #pragma unroll
    for (int g = 0; g < 4; ++g) {
        const int row = g * H_ + hh;
        wih[g]  = W_ih[row];
        bias[g] = b_ih[row] + b_hh[row];
        #pragma unroll
        for (int j = 0; j < H_; ++j)
            Wg_[g][j] = W_hh[row * H_ + j];
    }

    hl[half][hh] = 0.f;                 // h0 = 0
    if (hh < 2) hl[half][H_ + hh] = 0.f; // pad [22],[23] for float4 reads
    float creg = 0.f;
    const float* xp = xin + (size_t)seq * T_;
    float xc = xp[0];
    __hip_bfloat16* hout = hsw + ((size_t)b * T_ * (H_ * H_)) + c * H_ + hh;
    const float4* hv = reinterpret_cast<const float4*>(hl[half]);

    for (int t = 0; t < T_; ++t) {
        const float xn = (t + 1 < T_) ? xp[t + 1] : 0.f;

        __builtin_amdgcn_wave_barrier();
        float hj[24];
        #pragma unroll
        for (int q = 0; q < 6; ++q)
            *reinterpret_cast<float4*>(&hj[4 * q]) = hv[q];  // 6x ds_read_b128
        __builtin_amdgcn_wave_barrier();

        float a0 = fmaf(xc, wih[0], bias[0]);
        float a1 = fmaf(xc, wih[1], bias[1]);
        float a2 = fmaf(xc, wih[2], bias[2]);
        float a3 = fmaf(xc, wih[3], bias[3]);
        #pragma unroll
        for (int j = 0; j < H_; ++j) {
            a0 = fmaf(Wg_[0][j], hj[j], a0);
            a1 = fmaf(Wg_[1][j], hj[j], a1);
            a2 = fmaf(Wg_[2][j], hj[j], a2);
            a3 = fmaf(Wg_[3][j], hj[j], a3);
        }
        const float ig = sigm(a0);
        const float fg = sigm(a1);
        const float gg = tanhfast(a2);
        const float og = sigm(a3);
        creg = fmaf(fg, creg, ig * gg);
        const float hnew = og * tanhfast(creg);
        hl[half][hh] = hnew;            // ordered after this step's reads
        __builtin_amdgcn_wave_barrier();
        hout[0] = __float2bfloat16(hnew);
        hout += H_ * H_;
        xc = xn;
    }
}

// ---------------------------------------------------------------------------
// Kernel 2: conv(22ch, kh=22) + bias + ELU + BN(eval) + AvgPool(100).
// One block per (b, pool window p); 128 threads; tile 4t x 2k (110 active).
// Bank-conflict fixes vs round 3:
//  - thread rows are t4 + 10*i (group stride 244 dw = 20 mod 32 -> 8 bank
//    windows, <=2-way = free) instead of 4*t4..4*t4+3 (976 dw = 16 mod 32
//    -> 2 windows, ~5-way conflict).
//  - weights chunk-major: wl4[cch*22 + k] (k-group stride 8 dw -> ~2.7-way)
//    instead of k-major rows (976 dw stride -> ~5-way).
// All 110 threads now active in every phase (rows split 40/40/20).
// ---------------------------------------------------------------------------
__global__ __launch_bounds__(128) void conv_k(
    const __hip_bfloat16* __restrict__ hsw,  // [B_][T_][22][22]
    const float* __restrict__ conv_w,        // [22][22][22]
    const float* __restrict__ conv_b,        // [22]
    const float* __restrict__ bn_g,
    const float* __restrict__ bn_b,
    const float* __restrict__ bn_m,
    const float* __restrict__ bn_v,
    float* __restrict__ pooled)              // [B_][22][10]
{
    __shared__ __align__(16) __hip_bfloat16 wl[61 * 22 * 8];  // [cch][k][8]
    __shared__ __align__(16) __hip_bfloat16 hl[40 * CSTR];
    __shared__ float pp[22 * TP];

    const int tid = threadIdx.x;
    const int b = blockIdx.x / TP;
    const int p = blockIdx.x - b * TP;

    // zero pad elems e=4..7 of chunk 60 (dot positions 484..487)
    if (tid < 22)
        *reinterpret_cast<uint2*>(&wl[(60 * 22 + tid) * 8 + 4]) = make_uint2(0u, 0u);
    // stage conv_w: linear coalesced read; conv_w[k][i][r] -> dot d'=r*22+i,
    // wl[(d'/8)*22 + k][d'%8]
    for (int d = tid; d < 22 * 484; d += 128) {
        const float w = conv_w[d];
        const int k = d / 484, rem = d - k * 484;
        const int i2 = rem / 22, r = rem - i2 * 22;
        const int dp = r * 22 + i2;
        wl[((dp >> 3) * 22 + k) * 8 + (dp & 7)] = __float2bfloat16(w);
    }

    const int k2 = tid % 11;          // k pair index
    const int t4 = tid / 11;          // row group (0..9 valid)
    const bool act = (tid < 110);
    const int k0 = 2 * k2, k1 = 2 * k2 + 1;

    float cb[2], mn[2], bt[2], inv[2];
    #pragma unroll
    for (int j = 0; j < 2; ++j) {
        const int k = k0 + j;
        cb[j] = conv_b[k];
        mn[j] = bn_m[k];
        bt[j] = bn_b[k];
        inv[j] = bn_g[k] * __frsqrt_rn(bn_v[k] + 1e-5f);
    }

    float poolsum[2] = {0.f, 0.f};
    const __hip_bfloat16* src = hsw + ((size_t)b * T_ + (size_t)p * POOL) * 484;
    const uint4* wl4 = reinterpret_cast<const uint4*>(wl);
    const uint4* hl4 = reinterpret_cast<const uint4*>(hl);

    for (int ph = 0; ph < 3; ++ph) {
        const int rows = (ph == 2) ? 20 : 40;
        const uint2* gsrc = reinterpret_cast<const uint2*>(src + (size_t)(ph * 40) * 484);
        const int n2 = rows * 121;
        for (int idx = tid; idx < n2; idx += 128) {
            const int tr = idx / 121, col = idx - tr * 121;
            reinterpret_cast<uint2*>(&hl[tr * CSTR])[col] = gsrc[idx];
        }
        for (int idx = tid; idx < rows; idx += 128)
            *reinterpret_cast<uint2*>(&hl[idx * CSTR + 484]) = make_uint2(0u, 0u);
        __syncthreads();

        if (act) {
            const int nrt = (ph == 2) ? 2 : 4;     // rows t4 + 10*i
            float acc[4][2];
            #pragma unroll
            for (int i = 0; i < 4; ++i) { acc[i][0] = 0.f; acc[i][1] = 0.f; }
            for (int cch = 0; cch < 61; ++cch) {
                float wf[8], wg[8];
                unpk8(wl4[cch * 22 + k0], wf);
                unpk8(wl4[cch * 22 + k1], wg);
                for (int i = 0; i < nrt; ++i) {
                    float hf[8];
                    unpk8(hl4[(t4 + 10 * i) * 61 + cch], hf);
                    #pragma unroll
                    for (int e = 0; e < 8; ++e) {
                        acc[i][0] = fmaf(hf[e], wf[e], acc[i][0]);
                        acc[i][1] = fmaf(hf[e], wg[e], acc[i][1]);
                    }
                }
            }
            const int nv = (ph == 2) ? 2 : 4;
            for (int i = 0; i < nv; ++i) {
                #pragma unroll
                for (int j = 0; j < 2; ++j) {
                    const float s = acc[i][j] + cb[j];
                    const float e = (s > 0.f) ? s : (__expf(s) - 1.f);
                    poolsum[j] += fmaf(e - mn[j], inv[j], bt[j]);
                }
            }
        }
        __syncthreads();
    }

    if (act) {
        pp[k0 * TP + t4] = poolsum[0];
        pp[k1 * TP + t4] = poolsum[1];
    }
    __syncthreads();
    if (tid < 22) {
        float s = 0.f;
        #pragma unroll
        for (int q = 0; q < TP; ++q) s += pp[tid * TP + q];
        pooled[((size_t)b * 22 + tid) * TP + p] = s * 0.01f;
    }
}

// ---------------------------------------------------------------------------
// Kernel 3: FC [64,220] x [220,4]^T + bias -> fp32 out. One thread per output.
// ---------------------------------------------------------------------------
__global__ __launch_bounds__(256) void fc_k(
    const float* __restrict__ pooled,  // [64][220] (idx = k*10+p)
    const float* __restrict__ fc_w,    // [4][220]
    const float* __restrict__ fc_b,    // [4]
    float* __restrict__ out)           // [64][4]
{
    const int tid = threadIdx.x;
    const int b = tid >> 2, n = tid & 3;
    const float* pv = pooled + b * 220;
    const float* wv = fc_w + n * 220;
    float s = fc_b[n];
    #pragma unroll 4
    for (int j = 0; j < 220; ++j)
        s = fmaf(pv[j], wv[j], s);
    out[tid] = s;
}

extern "C" void kernel_launch(void* const* d_in, const int* in_sizes, int n_in,
                              void* d_out, int out_size, void* d_ws, size_t ws_size,
                              hipStream_t stream) {
    const float* xin    = (const float*)d_in[0];
    const float* W_ih   = (const float*)d_in[1];
    const float* W_hh   = (const float*)d_in[2];
    const float* b_ih   = (const float*)d_in[3];
    const float* b_hh   = (const float*)d_in[4];
    const float* conv_w = (const float*)d_in[5];
    const float* conv_b = (const float*)d_in[6];
    const float* bn_g   = (const float*)d_in[7];
    const float* bn_b   = (const float*)d_in[8];
    const float* bn_m   = (const float*)d_in[9];
    const float* bn_v   = (const float*)d_in[10];
    const float* fc_w   = (const float*)d_in[11];
    const float* fc_b   = (const float*)d_in[12];

    __hip_bfloat16* hsw = (__hip_bfloat16*)d_ws;                        // 61,952,000 B
    float* pooled = (float*)((char*)d_ws + (size_t)B_ * T_ * 484 * 2);  // 56,320 B

    lstm_k<<<NSEQ / 2, 64, 0, stream>>>(xin, W_ih, W_hh, b_ih, b_hh, hsw);
    conv_k<<<B_ * TP, 128, 0, stream>>>(hsw, conv_w, conv_b, bn_g, bn_b, bn_m, bn_v, pooled);
    fc_k<<<1, 256, 0, stream>>>(pooled, fc_w, fc_b, (float*)d_out);
}

// Round 5
// 640.411 us; speedup vs baseline: 1.1503x; 1.1131x over previous
//
#include <hip/hip_runtime.h>
#include <hip/hip_bf16.h>
#include <cstddef>

#define H_   22
#define T_   1000
#define B_   64
#define NSEQ (B_ * H_)      // 1408 sequences (B*C, C==22)
#define KP   22             // conv out channels
#define TP   10             // pooled time positions
#define POOL 100
#define CSTR 488            // hl row stride in fp16 (484 pad-> 488 = 61 uint4)

typedef _Float16 half2_t __attribute__((ext_vector_type(2)));

__device__ __forceinline__ float sigm(float x) {
    return __fdividef(1.f, 1.f + __expf(-x));     // saturates correctly
}
__device__ __forceinline__ float tanhfast(float x) {
    return 1.f - __fdividef(2.f, __expf(2.f * x) + 1.f);
}

// ---------------------------------------------------------------------------
// Kernel 1: batched independent LSTMs (fp32 in, fp16 hs out).
// 1 wave / block, 2 sequences / wave: lane = (half = lane>>5, hh = lane&31),
// lanes hh>=22 idle. Each lane holds its 4 gate rows of W_hh in VGPRs.
// amdgpu_waves_per_eu(1,1): round-4 showed __launch_bounds__(64,1) only sets
// the occupancy FLOOR — allocator still targeted 8 waves/EU (VGPR_Count=64),
// spilling ~30 values to scratch; per-step spill reloads = 2.88 GB FETCH on
// the serial critical path. Pinning max waves/EU=1 gives the full 512-VGPR
// budget -> no spill. (Grid is 704 waves on 1024 SIMDs; 1 wave/EU is free.)
// h-exchange via LDS (write b32, read back 6x ds_read_b128, broadcast reads);
// single-wave block => DS pipe in-order; wave_barrier() pins compiler order.
// hs layout: [b][t][c][h] (contiguous 484-elem dot vector per (b,t)).
// ---------------------------------------------------------------------------
__global__ __launch_bounds__(64)
__attribute__((amdgpu_waves_per_eu(1, 1)))
void lstm_k(
    const float* __restrict__ xin,   // [NSEQ][T_]
    const float* __restrict__ W_ih,  // [88]
    const float* __restrict__ W_hh,  // [88][22]
    const float* __restrict__ b_ih,  // [88]
    const float* __restrict__ b_hh,  // [88]
    _Float16* __restrict__ hsw)      // [B_][T_][22][22]
{
    __shared__ __align__(16) float hl[2][24];
    const int lane = threadIdx.x;
    const int half = lane >> 5;
    const int hh   = lane & 31;
    if (hh >= H_) return;
    const int seq = blockIdx.x * 2 + half;
    const int b   = seq / H_;
    const int c   = seq - b * H_;

    float Wg_[4][H_];
    float wih[4], bias[4];
    #pragma unroll
    for (int g = 0; g < 4; ++g) {
        const int row = g * H_ + hh;
        wih[g]  = W_ih[row];
        bias[g] = b_ih[row] + b_hh[row];
        #pragma unroll
        for (int j = 0; j < H_; ++j)
            Wg_[g][j] = W_hh[row * H_ + j];
    }

    hl[half][hh] = 0.f;                  // h0 = 0
    if (hh < 2) hl[half][H_ + hh] = 0.f; // pad [22],[23] for float4 reads
    float creg = 0.f;
    const float* xp = xin + (size_t)seq * T_;
    float xc = xp[0];
    _Float16* hout = hsw + ((size_t)b * T_ * (H_ * H_)) + c * H_ + hh;
    const float4* hv = reinterpret_cast<const float4*>(hl[half]);

    for (int t = 0; t < T_; ++t) {
        const float xn = (t + 1 < T_) ? xp[t + 1] : 0.f;

        __builtin_amdgcn_wave_barrier();
        float hj[24];
        #pragma unroll
        for (int q = 0; q < 6; ++q)
            *reinterpret_cast<float4*>(&hj[4 * q]) = hv[q];  // 6x ds_read_b128
        __builtin_amdgcn_wave_barrier();

        float a0 = fmaf(xc, wih[0], bias[0]);
        float a1 = fmaf(xc, wih[1], bias[1]);
        float a2 = fmaf(xc, wih[2], bias[2]);
        float a3 = fmaf(xc, wih[3], bias[3]);
        #pragma unroll
        for (int j = 0; j < H_; ++j) {
            a0 = fmaf(Wg_[0][j], hj[j], a0);
            a1 = fmaf(Wg_[1][j], hj[j], a1);
            a2 = fmaf(Wg_[2][j], hj[j], a2);
            a3 = fmaf(Wg_[3][j], hj[j], a3);
        }
        const float ig = sigm(a0);
        const float fg = sigm(a1);
        const float gg = tanhfast(a2);
        const float og = sigm(a3);
        creg = fmaf(fg, creg, ig * gg);
        const float hnew = og * tanhfast(creg);
        hl[half][hh] = hnew;             // ordered after this step's reads
        __builtin_amdgcn_wave_barrier();
        hout[0] = (_Float16)hnew;
        hout += H_ * H_;
        xc = xn;
    }
}

// ---------------------------------------------------------------------------
// Kernel 2: conv(22ch, kh=22) + bias + ELU + BN(eval) + AvgPool(100).
// One block per (b, pool window p); 256 threads, 220 active: k = tid%22,
// t5 = tid/22 (0..9); each thread: 1 out-channel x 10 rows (t5 + 10i).
// fp16 hs + v_dot2_f32_f16 (__builtin_amdgcn_fdot2): no unpack VALU, 2 MAC
// per op, fp32 accumulate. h-tile LDS reads are wave-broadcast (lanes with
// equal t5 hit the same address). Phased staging 40/40/20 rows.
// ---------------------------------------------------------------------------
__global__ __launch_bounds__(256) void conv_k(
    const _Float16* __restrict__ hsw,        // [B_][T_][22][22]
    const float* __restrict__ conv_w,        // [22][22][22]
    const float* __restrict__ conv_b,        // [22]
    const float* __restrict__ bn_g,
    const float* __restrict__ bn_b,
    const float* __restrict__ bn_m,
    const float* __restrict__ bn_v,
    float* __restrict__ pooled)              // [B_][22][10]
{
    __shared__ __align__(16) _Float16 wl[61 * 22 * 8];  // [cch][k][8]
    __shared__ __align__(16) _Float16 hl[40 * CSTR];
    __shared__ float pp[22 * TP];

    const int tid = threadIdx.x;
    const int b = blockIdx.x / TP;
    const int p = blockIdx.x - b * TP;

    // zero pad elems e=4..7 of chunk 60 (dot positions 484..487)
    if (tid < 22)
        *reinterpret_cast<uint2*>(&wl[(60 * 22 + tid) * 8 + 4]) = make_uint2(0u, 0u);
    // stage conv_w: linear coalesced read; conv_w[k][i][r] -> dot dp=r*22+i,
    // wl[(dp/8)*22 + k][dp%8]
    for (int d = tid; d < 22 * 484; d += 256) {
        const float w = conv_w[d];
        const int k = d / 484, rem = d - k * 484;
        const int i2 = rem / 22, r = rem - i2 * 22;
        const int dp = r * 22 + i2;
        wl[((dp >> 3) * 22 + k) * 8 + (dp & 7)] = (_Float16)w;
    }

    const int k  = tid % 22;          // out channel
    const int t5 = tid / 22;          // row group (0..9 valid)
    const bool act = (tid < 220);

    const float cb = conv_b[k];
    const float mn = bn_m[k];
    const float bt = bn_b[k];
    const float inv = bn_g[k] * __frsqrt_rn(bn_v[k] + 1e-5f);

    float poolsum = 0.f;
    const _Float16* src = hsw + ((size_t)b * T_ + (size_t)p * POOL) * 484;
    const uint4* wl4 = reinterpret_cast<const uint4*>(wl);
    const uint4* hl4 = reinterpret_cast<const uint4*>(hl);

    for (int ph = 0; ph < 3; ++ph) {
        const int rows = (ph == 2) ? 20 : 40;
        const uint2* gsrc = reinterpret_cast<const uint2*>(src + (size_t)(ph * 40) * 484);
        const int n2 = rows * 121;
        for (int idx = tid; idx < n2; idx += 256) {
            const int tr = idx / 121, col = idx - tr * 121;
            reinterpret_cast<uint2*>(&hl[tr * CSTR])[col] = gsrc[idx];
        }
        for (int idx = tid; idx < rows; idx += 256)
            *reinterpret_cast<uint2*>(&hl[idx * CSTR + 484]) = make_uint2(0u, 0u);
        __syncthreads();

        if (act) {
            const int nrt = (ph == 2) ? 2 : 4;     // rows t5 + 10*i
            float acc[4] = {0.f, 0.f, 0.f, 0.f};
            for (int cch = 0; cch < 61; ++cch) {
                const uint4 wv = wl4[cch * 22 + k];
                const half2_t* w2 = reinterpret_cast<const half2_t*>(&wv);
                for (int i = 0; i < nrt; ++i) {
                    const uint4 hv = hl4[(t5 + 10 * i) * 61 + cch];
                    const half2_t* h2 = reinterpret_cast<const half2_t*>(&hv);
                    acc[i] = __builtin_amdgcn_fdot2(h2[0], w2[0], acc[i], false);
                    acc[i] = __builtin_amdgcn_fdot2(h2[1], w2[1], acc[i], false);
                    acc[i] = __builtin_amdgcn_fdot2(h2[2], w2[2], acc[i], false);
                    acc[i] = __builtin_amdgcn_fdot2(h2[3], w2[3], acc[i], false);
                }
            }
            const int nv = (ph == 2) ? 2 : 4;
            for (int i = 0; i < nv; ++i) {
                const float s = acc[i] + cb;
                const float e = (s > 0.f) ? s : (__expf(s) - 1.f);
                poolsum += fmaf(e - mn, inv, bt);
            }
        }
        __syncthreads();
    }

    if (act) pp[k * TP + t5] = poolsum;
    __syncthreads();
    if (tid < 22) {
        float s = 0.f;
        #pragma unroll
        for (int q = 0; q < TP; ++q) s += pp[tid * TP + q];
        pooled[((size_t)b * 22 + tid) * TP + p] = s * 0.01f;
    }
}

// ---------------------------------------------------------------------------
// Kernel 3: FC [64,220] x [220,4]^T + bias -> fp32 out. One thread per output.
// ---------------------------------------------------------------------------
__global__ __launch_bounds__(256) void fc_k(
    const float* __restrict__ pooled,  // [64][220] (idx = k*10+p)
    const float* __restrict__ fc_w,    // [4][220]
    const float* __restrict__ fc_b,    // [4]
    float* __restrict__ out)           // [64][4]
{
    const int tid = threadIdx.x;
    const int b = tid >> 2, n = tid & 3;
    const float* pv = pooled + b * 220;
    const float* wv = fc_w + n * 220;
    float s = fc_b[n];
    #pragma unroll 4
    for (int j = 0; j < 220; ++j)
        s = fmaf(pv[j], wv[j], s);
    out[tid] = s;
}

extern "C" void kernel_launch(void* const* d_in, const int* in_sizes, int n_in,
                              void* d_out, int out_size, void* d_ws, size_t ws_size,
                              hipStream_t stream) {
    const float* xin    = (const float*)d_in[0];
    const float* W_ih   = (const float*)d_in[1];
    const float* W_hh   = (const float*)d_in[2];
    const float* b_ih   = (const float*)d_in[3];
    const float* b_hh   = (const float*)d_in[4];
    const float* conv_w = (const float*)d_in[5];
    const float* conv_b = (const float*)d_in[6];
    const float* bn_g   = (const float*)d_in[7];
    const float* bn_b   = (const float*)d_in[8];
    const float* bn_m   = (const float*)d_in[9];
    const float* bn_v   = (const float*)d_in[10];
    const float* fc_w   = (const float*)d_in[11];
    const float* fc_b   = (const float*)d_in[12];

    _Float16* hsw = (_Float16*)d_ws;                                    // 61,952,000 B
    float* pooled = (float*)((char*)d_ws + (size_t)B_ * T_ * 484 * 2);  // 56,320 B

    lstm_k<<<NSEQ / 2, 64, 0, stream>>>(xin, W_ih, W_hh, b_ih, b_hh, hsw);
    conv_k<<<B_ * TP, 256, 0, stream>>>(hsw, conv_w, conv_b, bn_g, bn_b, bn_m, bn_v, pooled);
    fc_k<<<1, 256, 0, stream>>>(pooled, fc_w, fc_b, (float*)d_out);
}

// Round 6
// 516.415 us; speedup vs baseline: 1.4265x; 1.2401x over previous
//
#include <hip/hip_runtime.h>
#include <hip/hip_bf16.h>
#include <cstddef>

#define H_   22
#define T_   1000
#define B_   64
#define NSEQ (B_ * H_)      // 1408 sequences (B*C, C==22)
#define KP   22             // conv out channels
#define TP   10             // pooled time positions
#define POOL 100
#define CSTR 488            // hl row stride in fp16 (484 pad-> 488 = 61 uint4)
#define XCH  22             // x-prefetch chunk (steps); 1 lane-coalesced load/chunk
#define NCHK ((T_ + XCH - 1) / XCH)   // 46

typedef _Float16 half2_t __attribute__((ext_vector_type(2)));

__device__ __forceinline__ float sigm(float x) {
    return __fdividef(1.f, 1.f + __expf(-x));     // saturates correctly
}
__device__ __forceinline__ float tanhfast(float x) {
    return 1.f - __fdividef(2.f, __expf(2.f * x) + 1.f);
}

// ---------------------------------------------------------------------------
// Kernel 1: batched independent LSTMs (fp32 in, fp16 hs out).
// 1 wave / block, 2 sequences / wave: lane = (half = lane>>5, hh = lane&31),
// lanes hh>=22 idle (early return). Weights resident in VGPRs
// (amdgpu_waves_per_eu(1,1): VGPR budget 512; round-5 VGPR_Count=132, no
// spill). Round-5 insight: dur is pinned by the per-step serial chain, not
// memory traffic (FETCH is 2.9 MB, units are KB). Chain cuts this round:
//  - x staged via double-buffered LDS ring (1 coalesced global load + 1
//    vmcnt wait per 22 steps). Per-step x read = prefetchable ds_read_b32;
//    the per-step hsw store is never vmcnt-waited inside the step loop.
//  - gate dot chains split 2x11 (8 independent accumulators): 88 -> ~48 cyc.
// h-exchange via LDS write b32 / 6x ds_read_b128; single-wave block => DS
// pipe in-order per wave; wave_barrier() pins compiler ordering.
// hs layout: [b][t][c][h] (contiguous 484-elem dot vector per (b,t)).
// ---------------------------------------------------------------------------
__global__ __launch_bounds__(64)
__attribute__((amdgpu_waves_per_eu(1, 1)))
void lstm_k(
    const float* __restrict__ xin,   // [NSEQ][T_]
    const float* __restrict__ W_ih,  // [88]
    const float* __restrict__ W_hh,  // [88][22]
    const float* __restrict__ b_ih,  // [88]
    const float* __restrict__ b_hh,  // [88]
    _Float16* __restrict__ hsw)      // [B_][T_][22][22]
{
    __shared__ __align__(16) float hl[2][24];
    __shared__ float xb[2][2][XCH + 2];   // [buf][half][step-in-chunk]
    const int lane = threadIdx.x;
    const int half = lane >> 5;
    const int hh   = lane & 31;
    if (hh >= H_) return;
    const int seq = blockIdx.x * 2 + half;
    const int b   = seq / H_;
    const int c   = seq - b * H_;

    float Wg_[4][H_];
    float wih[4], bias[4];
    #pragma unroll
    for (int g = 0; g < 4; ++g) {
        const int row = g * H_ + hh;
        wih[g]  = W_ih[row];
        bias[g] = b_ih[row] + b_hh[row];
        #pragma unroll
        for (int j = 0; j < H_; ++j)
            Wg_[g][j] = W_hh[row * H_ + j];
    }

    hl[half][hh] = 0.f;                  // h0 = 0
    if (hh < 2) hl[half][H_ + hh] = 0.f; // pad [22],[23] for float4 reads
    float creg = 0.f;
    const float* xp = xin + (size_t)seq * T_;
    xb[0][half][hh] = xp[hh];            // stage chunk 0 (hh < 22 < T_)
    _Float16* hout = hsw + ((size_t)b * T_ * (H_ * H_)) + c * H_ + hh;
    const float4* hv = reinterpret_cast<const float4*>(hl[half]);

    for (int chk = 0; chk < NCHK; ++chk) {
        // issue next chunk's coalesced load now; vmcnt-waited only at the
        // ds_write below (once per chunk, ~22 steps later)
        const int tn = (chk + 1) * XCH + hh;
        const float xv = (tn < T_) ? xp[tn] : 0.f;

        const int t0  = chk * XCH;
        const int nst = (t0 + XCH <= T_) ? XCH : (T_ - t0);
        const float* xrow = xb[chk & 1][half];

        #pragma unroll 2
        for (int s = 0; s < nst; ++s) {
            const float xc = xrow[s];    // ds_read_b32, prefetchable

            __builtin_amdgcn_wave_barrier();
            float hj[24];
            #pragma unroll
            for (int q = 0; q < 6; ++q)
                *reinterpret_cast<float4*>(&hj[4 * q]) = hv[q];  // ds_read_b128
            __builtin_amdgcn_wave_barrier();

            float a0 = fmaf(xc, wih[0], bias[0]);
            float a1 = fmaf(xc, wih[1], bias[1]);
            float a2 = fmaf(xc, wih[2], bias[2]);
            float a3 = fmaf(xc, wih[3], bias[3]);
            float b0 = 0.f, b1 = 0.f, b2 = 0.f, b3 = 0.f;
            #pragma unroll
            for (int j = 0; j < 11; ++j) {
                a0 = fmaf(Wg_[0][j], hj[j], a0);
                a1 = fmaf(Wg_[1][j], hj[j], a1);
                a2 = fmaf(Wg_[2][j], hj[j], a2);
                a3 = fmaf(Wg_[3][j], hj[j], a3);
            }
            #pragma unroll
            for (int j = 11; j < 22; ++j) {
                b0 = fmaf(Wg_[0][j], hj[j], b0);
                b1 = fmaf(Wg_[1][j], hj[j], b1);
                b2 = fmaf(Wg_[2][j], hj[j], b2);
                b3 = fmaf(Wg_[3][j], hj[j], b3);
            }
            a0 += b0; a1 += b1; a2 += b2; a3 += b3;

            const float ig = sigm(a0);
            const float fg = sigm(a1);
            const float gg = tanhfast(a2);
            const float og = sigm(a3);
            creg = fmaf(fg, creg, ig * gg);
            const float hnew = og * tanhfast(creg);
            hl[half][hh] = hnew;         // ordered after this step's reads
            __builtin_amdgcn_wave_barrier();
            hout[0] = (_Float16)hnew;    // fire-and-forget store
            hout += H_ * H_;
        }

        // publish next chunk's x (waits vmcnt for xv once per chunk)
        xb[(chk + 1) & 1][half][hh] = xv;
    }
}

// ---------------------------------------------------------------------------
// Kernel 2: conv(22ch, kh=22) + bias + ELU + BN(eval) + AvgPool(100).
// One block per (b, pool window p); 256 threads, 220 active: k = tid%22,
// t5 = tid/22 (0..9); each thread: 1 out-channel x 10 rows (t5 + 10i).
// fp16 hs + v_dot2_f32_f16 (__builtin_amdgcn_fdot2): no unpack VALU, 2 MAC
// per op, fp32 accumulate. h-tile LDS reads are wave-broadcast (lanes with
// equal t5 hit the same address). Phased staging 40/40/20 rows.
// ---------------------------------------------------------------------------
__global__ __launch_bounds__(256) void conv_k(
    const _Float16* __restrict__ hsw,        // [B_][T_][22][22]
    const float* __restrict__ conv_w,        // [22][22][22]
    const float* __restrict__ conv_b,        // [22]
    const float* __restrict__ bn_g,
    const float* __restrict__ bn_b,
    const float* __restrict__ bn_m,
    const float* __restrict__ bn_v,
    float* __restrict__ pooled)              // [B_][22][10]
{
    __shared__ __align__(16) _Float16 wl[61 * 22 * 8];  // [cch][k][8]
    __shared__ __align__(16) _Float16 hl[40 * CSTR];
    __shared__ float pp[22 * TP];

    const int tid = threadIdx.x;
    const int b = blockIdx.x / TP;
    const int p = blockIdx.x - b * TP;

    // zero pad elems e=4..7 of chunk 60 (dot positions 484..487)
    if (tid < 22)
        *reinterpret_cast<uint2*>(&wl[(60 * 22 + tid) * 8 + 4]) = make_uint2(0u, 0u);
    // stage conv_w: linear coalesced read; conv_w[k][i][r] -> dot dp=r*22+i,
    // wl[(dp/8)*22 + k][dp%8]
    for (int d = tid; d < 22 * 484; d += 256) {
        const float w = conv_w[d];
        const int k = d / 484, rem = d - k * 484;
        const int i2 = rem / 22, r = rem - i2 * 22;
        const int dp = r * 22 + i2;
        wl[((dp >> 3) * 22 + k) * 8 + (dp & 7)] = (_Float16)w;
    }

    const int k  = tid % 22;          // out channel
    const int t5 = tid / 22;          // row group (0..9 valid)
    const bool act = (tid < 220);

    const float cb = conv_b[k];
    const float mn = bn_m[k];
    const float bt = bn_b[k];
    const float inv = bn_g[k] * __frsqrt_rn(bn_v[k] + 1e-5f);

    float poolsum = 0.f;
    const _Float16* src = hsw + ((size_t)b * T_ + (size_t)p * POOL) * 484;
    const uint4* wl4 = reinterpret_cast<const uint4*>(wl);
    const uint4* hl4 = reinterpret_cast<const uint4*>(hl);

    for (int ph = 0; ph < 3; ++ph) {
        const int rows = (ph == 2) ? 20 : 40;
        const uint2* gsrc = reinterpret_cast<const uint2*>(src + (size_t)(ph * 40) * 484);
        const int n2 = rows * 121;
        for (int idx = tid; idx < n2; idx += 256) {
            const int tr = idx / 121, col = idx - tr * 121;
            reinterpret_cast<uint2*>(&hl[tr * CSTR])[col] = gsrc[idx];
        }
        for (int idx = tid; idx < rows; idx += 256)
            *reinterpret_cast<uint2*>(&hl[idx * CSTR + 484]) = make_uint2(0u, 0u);
        __syncthreads();

        if (act) {
            const int nrt = (ph == 2) ? 2 : 4;     // rows t5 + 10*i
            float acc[4] = {0.f, 0.f, 0.f, 0.f};
            for (int cch = 0; cch < 61; ++cch) {
                const uint4 wv = wl4[cch * 22 + k];
                const half2_t* w2 = reinterpret_cast<const half2_t*>(&wv);
                for (int i = 0; i < nrt; ++i) {
                    const uint4 hv = hl4[(t5 + 10 * i) * 61 + cch];
                    const half2_t* h2 = reinterpret_cast<const half2_t*>(&hv);
                    acc[i] = __builtin_amdgcn_fdot2(h2[0], w2[0], acc[i], false);
                    acc[i] = __builtin_amdgcn_fdot2(h2[1], w2[1], acc[i], false);
                    acc[i] = __builtin_amdgcn_fdot2(h2[2], w2[2], acc[i], false);
                    acc[i] = __builtin_amdgcn_fdot2(h2[3], w2[3], acc[i], false);
                }
            }
            const int nv = (ph == 2) ? 2 : 4;
            for (int i = 0; i < nv; ++i) {
                const float s = acc[i] + cb;
                const float e = (s > 0.f) ? s : (__expf(s) - 1.f);
                poolsum += fmaf(e - mn, inv, bt);
            }
        }
        __syncthreads();
    }

    if (act) pp[k * TP + t5] = poolsum;
    __syncthreads();
    if (tid < 22) {
        float s = 0.f;
        #pragma unroll
        for (int q = 0; q < TP; ++q) s += pp[tid * TP + q];
        pooled[((size_t)b * 22 + tid) * TP + p] = s * 0.01f;
    }
}

// ---------------------------------------------------------------------------
// Kernel 3: FC [64,220] x [220,4]^T + bias -> fp32 out. One thread per output.
// ---------------------------------------------------------------------------
__global__ __launch_bounds__(256) void fc_k(
    const float* __restrict__ pooled,  // [64][220] (idx = k*10+p)
    const float* __restrict__ fc_w,    // [4][220]
    const float* __restrict__ fc_b,    // [4]
    float* __restrict__ out)           // [64][4]
{
    const int tid = threadIdx.x;
    const int b = tid >> 2, n = tid & 3;
    const float* pv = pooled + b * 220;
    const float* wv = fc_w + n * 220;
    float s = fc_b[n];
    #pragma unroll 4
    for (int j = 0; j < 220; ++j)
        s = fmaf(pv[j], wv[j], s);
    out[tid] = s;
}

extern "C" void kernel_launch(void* const* d_in, const int* in_sizes, int n_in,
                              void* d_out, int out_size, void* d_ws, size_t ws_size,
                              hipStream_t stream) {
    const float* xin    = (const float*)d_in[0];
    const float* W_ih   = (const float*)d_in[1];
    const float* W_hh   = (const float*)d_in[2];
    const float* b_ih   = (const float*)d_in[3];
    const float* b_hh   = (const float*)d_in[4];
    const float* conv_w = (const float*)d_in[5];
    const float* conv_b = (const float*)d_in[6];
    const float* bn_g   = (const float*)d_in[7];
    const float* bn_b   = (const float*)d_in[8];
    const float* bn_m   = (const float*)d_in[9];
    const float* bn_v   = (const float*)d_in[10];
    const float* fc_w   = (const float*)d_in[11];
    const float* fc_b   = (const float*)d_in[12];

    _Float16* hsw = (_Float16*)d_ws;                                    // 61,952,000 B
    float* pooled = (float*)((char*)d_ws + (size_t)B_ * T_ * 484 * 2);  // 56,320 B

    lstm_k<<<NSEQ / 2, 64, 0, stream>>>(xin, W_ih, W_hh, b_ih, b_hh, hsw);
    conv_k<<<B_ * TP, 256, 0, stream>>>(hsw, conv_w, conv_b, bn_g, bn_b, bn_m, bn_v, pooled);
    fc_k<<<1, 256, 0, stream>>>(pooled, fc_w, fc_b, (float*)d_out);
}

// Round 7
// 485.864 us; speedup vs baseline: 1.5162x; 1.0629x over previous
//
#include <hip/hip_runtime.h>
#include <hip/hip_bf16.h>
#include <cstddef>

#define H_   22
#define T_   1000
#define B_   64
#define NSEQ (B_ * H_)      // 1408 sequences (B*C, C==22)
#define KP   22             // conv out channels
#define TP   10             // pooled time positions
#define POOL 100
#define CSTR 488            // hl row stride in fp16 (484 pad-> 488 = 61 uint4)
#define XCH  22             // x-prefetch chunk (steps); 1 lane-coalesced load/chunk
#define NCHK ((T_ + XCH - 1) / XCH)   // 46

typedef _Float16 half2_t __attribute__((ext_vector_type(2)));

__device__ __forceinline__ float sigm(float x) {
    return __fdividef(1.f, 1.f + __expf(-x));     // saturates correctly
}
__device__ __forceinline__ float tanhfast(float x) {
    return 1.f - __fdividef(2.f, __expf(2.f * x) + 1.f);
}

// ---------------------------------------------------------------------------
// Kernel 1: batched independent LSTMs (fp32 in, fp16 hs out).
// 1 wave / block, 2 sequences / wave: lane = (half = lane>>5, hh = lane&31),
// lanes hh>=22 idle (early return). Round-6 model: per-step ~907 cyc =
// ~260 cyc VALU issue (88 fp32 FMA = 176) + LDS h-round-trip + activation
// chain; nothing hideable at 0.7 waves/SIMD. Round-7 cuts the two largest
// items:
//  - W_hh held as 44 packed half2 VGPRs; recurrent dot = 44 v_dot2_f32_f16
//    (2 MAC/inst, fp32 acc) instead of 88 v_fma_f32 -> issue 176 -> 88 cyc.
//  - h exchanged through LDS as fp16: round-trip read = 3x ds_read_b128
//    (was 6). ds_write_b16 publishes each lane's h.
// x staged via double-buffered LDS ring (1 coalesced load + 1 vmcnt wait
// per 22 steps). Weights stay VGPR-resident via amdgpu_waves_per_eu(1,1).
// Single-wave block => DS pipe in-order; wave_barrier() pins ordering.
// hs layout: [b][t][c][h] (contiguous 484-elem dot vector per (b,t)).
// ---------------------------------------------------------------------------
__global__ __launch_bounds__(64)
__attribute__((amdgpu_waves_per_eu(1, 1)))
void lstm_k(
    const float* __restrict__ xin,   // [NSEQ][T_]
    const float* __restrict__ W_ih,  // [88]
    const float* __restrict__ W_hh,  // [88][22]
    const float* __restrict__ b_ih,  // [88]
    const float* __restrict__ b_hh,  // [88]
    _Float16* __restrict__ hsw)      // [B_][T_][22][22]
{
    __shared__ __align__(16) _Float16 hl[2][24];   // fp16 h + 2 pad
    __shared__ float xb[2][2][XCH + 2];            // [buf][half][step-in-chunk]
    const int lane = threadIdx.x;
    const int half = lane >> 5;
    const int hh   = lane & 31;
    if (hh >= H_) return;
    const int seq = blockIdx.x * 2 + half;
    const int b   = seq / H_;
    const int c   = seq - b * H_;

    // packed fp16 W_hh rows: w2[g][j] = {W[g*22+hh][2j], W[g*22+hh][2j+1]}
    half2_t w2[4][11];
    float wih[4], bias[4];
    #pragma unroll
    for (int g = 0; g < 4; ++g) {
        const int row = g * H_ + hh;
        wih[g]  = W_ih[row];
        bias[g] = b_ih[row] + b_hh[row];
        #pragma unroll
        for (int j = 0; j < 11; ++j) {
            half2_t t;
            t[0] = (_Float16)W_hh[row * H_ + 2 * j];
            t[1] = (_Float16)W_hh[row * H_ + 2 * j + 1];
            w2[g][j] = t;
        }
    }

    hl[half][hh] = (_Float16)0.f;                    // h0 = 0
    if (hh < 2) hl[half][H_ + hh] = (_Float16)0.f;   // pad [22],[23]
    float creg = 0.f;
    const float* xp = xin + (size_t)seq * T_;
    xb[0][half][hh] = xp[hh];            // stage chunk 0 (hh < 22 < T_)
    _Float16* hout = hsw + ((size_t)b * T_ * (H_ * H_)) + c * H_ + hh;
    const uint4* hv = reinterpret_cast<const uint4*>(hl[half]);

    for (int chk = 0; chk < NCHK; ++chk) {
        // issue next chunk's coalesced load now; vmcnt-waited only at the
        // ds_write below (once per chunk, ~22 steps later)
        const int tn = (chk + 1) * XCH + hh;
        const float xv = (tn < T_) ? xp[tn] : 0.f;

        const int t0  = chk * XCH;
        const int nst = (t0 + XCH <= T_) ? XCH : (T_ - t0);
        const float* xrow = xb[chk & 1][half];

        #pragma unroll 2
        for (int s = 0; s < nst; ++s) {
            const float xc = xrow[s];    // ds_read_b32, prefetchable

            __builtin_amdgcn_wave_barrier();
            uint4 hr[3];
            #pragma unroll
            for (int q = 0; q < 3; ++q) hr[q] = hv[q];   // 3x ds_read_b128
            __builtin_amdgcn_wave_barrier();
            const half2_t* hp = reinterpret_cast<const half2_t*>(hr);

            float a0 = fmaf(xc, wih[0], bias[0]);
            float a1 = fmaf(xc, wih[1], bias[1]);
            float a2 = fmaf(xc, wih[2], bias[2]);
            float a3 = fmaf(xc, wih[3], bias[3]);
            float b0 = 0.f, b1 = 0.f, b2 = 0.f, b3 = 0.f;
            #pragma unroll
            for (int j = 0; j < 6; ++j) {
                a0 = __builtin_amdgcn_fdot2(hp[j], w2[0][j], a0, false);
                a1 = __builtin_amdgcn_fdot2(hp[j], w2[1][j], a1, false);
                a2 = __builtin_amdgcn_fdot2(hp[j], w2[2][j], a2, false);
                a3 = __builtin_amdgcn_fdot2(hp[j], w2[3][j], a3, false);
            }
            #pragma unroll
            for (int j = 6; j < 11; ++j) {
                b0 = __builtin_amdgcn_fdot2(hp[j], w2[0][j], b0, false);
                b1 = __builtin_amdgcn_fdot2(hp[j], w2[1][j], b1, false);
                b2 = __builtin_amdgcn_fdot2(hp[j], w2[2][j], b2, false);
                b3 = __builtin_amdgcn_fdot2(hp[j], w2[3][j], b3, false);
            }
            a0 += b0; a1 += b1; a2 += b2; a3 += b3;

            const float ig = sigm(a0);
            const float fg = sigm(a1);
            const float gg = tanhfast(a2);
            const float og = sigm(a3);
            creg = fmaf(fg, creg, ig * gg);
            const float hnew = og * tanhfast(creg);
            const _Float16 hf = (_Float16)hnew;
            hl[half][hh] = hf;           // ds_write_b16, after this step's reads
            __builtin_amdgcn_wave_barrier();
            hout[0] = hf;                // fire-and-forget global_store_short
            hout += H_ * H_;
        }

        // publish next chunk's x (waits vmcnt for xv once per chunk)
        xb[(chk + 1) & 1][half][hh] = xv;
    }
}

// ---------------------------------------------------------------------------
// Kernel 2: conv(22ch, kh=22) + bias + ELU + BN(eval) + AvgPool(100).
// One block per (b, pool window p); 256 threads, 220 active: k = tid%22,
// t5 = tid/22 (0..9); each thread: 1 out-channel x 10 rows (t5 + 10i).
// fp16 hs + v_dot2_f32_f16 (__builtin_amdgcn_fdot2): no unpack VALU, 2 MAC
// per op, fp32 accumulate. h-tile LDS reads are wave-broadcast (lanes with
// equal t5 hit the same address). Phased staging 40/40/20 rows.
// ---------------------------------------------------------------------------
__global__ __launch_bounds__(256) void conv_k(
    const _Float16* __restrict__ hsw,        // [B_][T_][22][22]
    const float* __restrict__ conv_w,        // [22][22][22]
    const float* __restrict__ conv_b,        // [22]
    const float* __restrict__ bn_g,
    const float* __restrict__ bn_b,
    const float* __restrict__ bn_m,
    const float* __restrict__ bn_v,
    float* __restrict__ pooled)              // [B_][22][10]
{
    __shared__ __align__(16) _Float16 wl[61 * 22 * 8];  // [cch][k][8]
    __shared__ __align__(16) _Float16 hl[40 * CSTR];
    __shared__ float pp[22 * TP];

    const int tid = threadIdx.x;
    const int b = blockIdx.x / TP;
    const int p = blockIdx.x - b * TP;

    // zero pad elems e=4..7 of chunk 60 (dot positions 484..487)
    if (tid < 22)
        *reinterpret_cast<uint2*>(&wl[(60 * 22 + tid) * 8 + 4]) = make_uint2(0u, 0u);
    // stage conv_w: linear coalesced read; conv_w[k][i][r] -> dot dp=r*22+i,
    // wl[(dp/8)*22 + k][dp%8]
    for (int d = tid; d < 22 * 484; d += 256) {
        const float w = conv_w[d];
        const int k = d / 484, rem = d - k * 484;
        const int i2 = rem / 22, r = rem - i2 * 22;
        const int dp = r * 22 + i2;
        wl[((dp >> 3) * 22 + k) * 8 + (dp & 7)] = (_Float16)w;
    }

    const int k  = tid % 22;          // out channel
    const int t5 = tid / 22;          // row group (0..9 valid)
    const bool act = (tid < 220);

    const float cb = conv_b[k];
    const float mn = bn_m[k];
    const float bt = bn_b[k];
    const float inv = bn_g[k] * __frsqrt_rn(bn_v[k] + 1e-5f);

    float poolsum = 0.f;
    const _Float16* src = hsw + ((size_t)b * T_ + (size_t)p * POOL) * 484;
    const uint4* wl4 = reinterpret_cast<const uint4*>(wl);
    const uint4* hl4 = reinterpret_cast<const uint4*>(hl);

    for (int ph = 0; ph < 3; ++ph) {
        const int rows = (ph == 2) ? 20 : 40;
        const uint2* gsrc = reinterpret_cast<const uint2*>(src + (size_t)(ph * 40) * 484);
        const int n2 = rows * 121;
        for (int idx = tid; idx < n2; idx += 256) {
            const int tr = idx / 121, col = idx - tr * 121;
            reinterpret_cast<uint2*>(&hl[tr * CSTR])[col] = gsrc[idx];
        }
        for (int idx = tid; idx < rows; idx += 256)
            *reinterpret_cast<uint2*>(&hl[idx * CSTR + 484]) = make_uint2(0u, 0u);
        __syncthreads();

        if (act) {
            const int nrt = (ph == 2) ? 2 : 4;     // rows t5 + 10*i
            float acc[4] = {0.f, 0.f, 0.f, 0.f};
            for (int cch = 0; cch < 61; ++cch) {
                const uint4 wv = wl4[cch * 22 + k];
                const half2_t* w2 = reinterpret_cast<const half2_t*>(&wv);
                for (int i = 0; i < nrt; ++i) {
                    const uint4 hv = hl4[(t5 + 10 * i) * 61 + cch];
                    const half2_t* h2 = reinterpret_cast<const half2_t*>(&hv);
                    acc[i] = __builtin_amdgcn_fdot2(h2[0], w2[0], acc[i], false);
                    acc[i] = __builtin_amdgcn_fdot2(h2[1], w2[1], acc[i], false);
                    acc[i] = __builtin_amdgcn_fdot2(h2[2], w2[2], acc[i], false);
                    acc[i] = __builtin_amdgcn_fdot2(h2[3], w2[3], acc[i], false);
                }
            }
            const int nv = (ph == 2) ? 2 : 4;
            for (int i = 0; i < nv; ++i) {
                const float s = acc[i] + cb;
                const float e = (s > 0.f) ? s : (__expf(s) - 1.f);
                poolsum += fmaf(e - mn, inv, bt);
            }
        }
        __syncthreads();
    }

    if (act) pp[k * TP + t5] = poolsum;
    __syncthreads();
    if (tid < 22) {
        float s = 0.f;
        #pragma unroll
        for (int q = 0; q < TP; ++q) s += pp[tid * TP + q];
        pooled[((size_t)b * 22 + tid) * TP + p] = s * 0.01f;
    }
}

// ---------------------------------------------------------------------------
// Kernel 3: FC [64,220] x [220,4]^T + bias -> fp32 out. One thread per output.
// ---------------------------------------------------------------------------
__global__ __launch_bounds__(256) void fc_k(
    const float* __restrict__ pooled,  // [64][220] (idx = k*10+p)
    const float* __restrict__ fc_w,    // [4][220]
    const float* __restrict__ fc_b,    // [4]
    float* __restrict__ out)           // [64][4]
{
    const int tid = threadIdx.x;
    const int b = tid >> 2, n = tid & 3;
    const float* pv = pooled + b * 220;
    const float* wv = fc_w + n * 220;
    float s = fc_b[n];
    #pragma unroll 4
    for (int j = 0; j < 220; ++j)
        s = fmaf(pv[j], wv[j], s);
    out[tid] = s;
}

extern "C" void kernel_launch(void* const* d_in, const int* in_sizes, int n_in,
                              void* d_out, int out_size, void* d_ws, size_t ws_size,
                              hipStream_t stream) {
    const float* xin    = (const float*)d_in[0];
    const float* W_ih   = (const float*)d_in[1];
    const float* W_hh   = (const float*)d_in[2];
    const float* b_ih   = (const float*)d_in[3];
    const float* b_hh   = (const float*)d_in[4];
    const float* conv_w = (const float*)d_in[5];
    const float* conv_b = (const float*)d_in[6];
    const float* bn_g   = (const float*)d_in[7];
    const float* bn_b   = (const float*)d_in[8];
    const float* bn_m   = (const float*)d_in[9];
    const float* bn_v   = (const float*)d_in[10];
    const float* fc_w   = (const float*)d_in[11];
    const float* fc_b   = (const float*)d_in[12];

    _Float16* hsw = (_Float16*)d_ws;                                    // 61,952,000 B
    float* pooled = (float*)((char*)d_ws + (size_t)B_ * T_ * 484 * 2);  // 56,320 B

    lstm_k<<<NSEQ / 2, 64, 0, stream>>>(xin, W_ih, W_hh, b_ih, b_hh, hsw);
    conv_k<<<B_ * TP, 256, 0, stream>>>(hsw, conv_w, conv_b, bn_g, bn_b, bn_m, bn_v, pooled);
    fc_k<<<1, 256, 0, stream>>>(pooled, fc_w, fc_b, (float*)d_out);
}